// Round 3
// baseline (136.884 us; speedup 1.0000x reference)
//
#include <hip/hip_runtime.h>
#include <stdint.h>

// N=4 batches, C=256, S=16, H*W=1024, K1=S*C=4096, 3 layers.
#define CC   256
#define SSL  16
#define NB   4
#define HWP  1024
#define K1   4096
#define EPSV 1e-5f

typedef __attribute__((ext_vector_type(8))) short bf16x8;
typedef __attribute__((ext_vector_type(4))) float f32x4;

__device__ __forceinline__ ushort f2bf(float f) {
    uint32_t u = __float_as_uint(f);
    uint32_t r = (u + 0x7FFFu + ((u >> 16) & 1u)) >> 16;   // RNE
    return (ushort)r;
}

// ---------------------------------------------------------------------------
// prep1: fused by blockIdx range (all three only read harness inputs):
//   [0,64)    flags[n][k][b]: 2=all 16 rows of slice k pos at col b, 1=any, 0=none
//   [64,320)  feats [n][c][p] fp32 -> fT [n][p][c] bf16 (LDS transpose)
//   [320,1088) conv_w fp32 -> bf16 copy, 16 elems/thread
__global__ __launch_bounds__(256) void prep1_kernel(const float* __restrict__ adj,
                                                    const float* __restrict__ feats,
                                                    const float* __restrict__ conv_w,
                                                    uint8_t* __restrict__ flags,
                                                    ushort* __restrict__ fT,
                                                    ushort* __restrict__ wb) {
    __shared__ float Ts[64][68];
    const int bid = blockIdx.x;
    const int t = threadIdx.x;
    if (bid < 64) {                       // ---- flags ----
        const int n = bid >> 4, k = bid & 15;
        const float* m = adj + (size_t)n * CC * CC;
        bool allp = true, anyp = false;
#pragma unroll
        for (int i = 0; i < 16; ++i) {
            float v = m[(size_t)(k * 16 + i) * CC + t];
            bool p = v > 0.0f;
            allp = allp && p;
            anyp = anyp || p;
        }
        flags[(size_t)bid * CC + t] = allp ? (uint8_t)2 : (anyp ? (uint8_t)1 : (uint8_t)0);
    } else if (bid < 320) {               // ---- featsT ----
        const int f = bid - 64;
        const int n = f >> 6, r = f & 63;
        const int c0 = (r >> 4) * 64, p0 = (r & 15) * 64;
        const float* src = feats + ((size_t)n * CC + c0) * HWP + p0;
        const int cr = t >> 2, pq = (t & 3) * 16;
#pragma unroll
        for (int i = 0; i < 4; ++i)
            *(float4*)&Ts[cr][pq + i * 4] = *(const float4*)(src + (size_t)cr * HWP + pq + i * 4);
        __syncthreads();
        const int pl = t >> 2, cc0 = (t & 3) * 16;
        ushort* dst = fT + ((size_t)n * HWP + p0 + pl) * CC + c0 + cc0;
#pragma unroll
        for (int a4 = 0; a4 < 4; ++a4) {
            ushort4 o;
            o.x = f2bf(Ts[cc0 + a4 * 4 + 0][pl]);
            o.y = f2bf(Ts[cc0 + a4 * 4 + 1][pl]);
            o.z = f2bf(Ts[cc0 + a4 * 4 + 2][pl]);
            o.w = f2bf(Ts[cc0 + a4 * 4 + 3][pl]);
            *(ushort4*)(dst + a4 * 4) = o;
        }
    } else {                              // ---- convw bf16 ----
        const int c = bid - 320;
        const int idx = (c * 256 + t) * 16;
#pragma unroll
        for (int i = 0; i < 4; ++i) {
            float4 v = *(const float4*)(conv_w + idx + i * 4);
            ushort4 o = {f2bf(v.x), f2bf(v.y), f2bf(v.z), f2bf(v.w)};
            *(ushort4*)(wb + idx + i * 4) = o;
        }
    }
}

// ---------------------------------------------------------------------------
// msst[n][b][k*256+a] = bf16( sel(flag[n,k,b], m[n,a,b]) )  — B^T layout (K-contig).
__global__ __launch_bounds__(256) void msst_kernel(const float* __restrict__ adj,
                                                   const uint8_t* __restrict__ flags,
                                                   ushort* __restrict__ msst) {
    const int n = blockIdx.y;
    const int at = blockIdx.x >> 2, bt = blockIdx.x & 3;
    const int a0 = at * 64, b0 = bt * 64;
    const float* m = adj + (size_t)n * CC * CC;
    __shared__ float Ms[64][68];
    __shared__ uint8_t Fl[16][64];
    const int t = threadIdx.x;
    {
        const int ar = t >> 2, bq = (t & 3) * 16;
        const float* src = m + (size_t)(a0 + ar) * CC + b0 + bq;
#pragma unroll
        for (int i = 0; i < 4; ++i)
            *(float4*)&Ms[ar][bq + i * 4] = *(const float4*)(src + i * 4);
        const int k = t >> 4, b4 = (t & 15) * 4;
        *(uchar4*)&Fl[k][b4] = *(const uchar4*)(flags + (size_t)(n * SSL + k) * CC + b0 + b4);
    }
    __syncthreads();
    const int bl = t >> 2, ac = (t & 3) * 16;
    ushort bx[16], bp[16];
#pragma unroll
    for (int i = 0; i < 16; ++i) {
        float x = Ms[ac + i][bl];
        bx[i] = f2bf(x);
        bp[i] = f2bf(fmaxf(x, 0.0f));
    }
    ushort* dst = msst + ((size_t)(n * CC + b0 + bl)) * K1 + a0 + ac;
#pragma unroll
    for (int k = 0; k < 16; ++k) {
        const uint8_t f = Fl[k][bl];
        ushort* dk = dst + k * CC;
#pragma unroll
        for (int a4 = 0; a4 < 4; ++a4) {
            ushort4 o;
            o.x = (f == 2) ? bx[a4 * 4 + 0] : ((f == 1) ? bp[a4 * 4 + 0] : (ushort)0);
            o.y = (f == 2) ? bx[a4 * 4 + 1] : ((f == 1) ? bp[a4 * 4 + 1] : (ushort)0);
            o.z = (f == 2) ? bx[a4 * 4 + 2] : ((f == 1) ? bp[a4 * 4 + 2] : (ushort)0);
            o.w = (f == 2) ? bx[a4 * 4 + 3] : ((f == 1) ? bp[a4 * 4 + 3] : (ushort)0);
            *(ushort4*)(dk + a4 * 4) = o;
        }
    }
}

// ---------------------------------------------------------------------------
// W_eff partial GEMM (bf16 MFMA). Output stored TRANSPOSED: wpartT[sp][ln][b][o],
// so each lane's 4 accumulator regs (consecutive rows o) form one contiguous
// float4 store. Grid (4 tiles, 12 ln, 8 sk).
__global__ __launch_bounds__(256) void weff_mfma(const ushort* __restrict__ Aw,
                                                 const ushort* __restrict__ Bm,
                                                 float* __restrict__ wpart) {
    const int tile = blockIdx.x;
    const int ln = blockIdx.y;
    const int sp = blockIdx.z;
    const int l = ln >> 2, n = ln & 3;
    const int trow = (tile >> 1) * 128, tcol = (tile & 1) * 128;
    const ushort* A = Aw + (size_t)l * CC * K1;
    const ushort* B = Bm + (size_t)n * CC * K1;
    __shared__ ushort Al[128][40];
    __shared__ ushort Bl[128][40];
    const int t = threadIdx.x;
    const int wv = t >> 6, L = t & 63;
    const int wr = (wv >> 1) * 64, wc = (wv & 1) * 64;
    const int l16 = L & 15, q = L >> 4;
    const int r0 = t >> 2, kq0 = (t & 3) * 8;
    f32x4 acc[4][4];
#pragma unroll
    for (int i = 0; i < 4; ++i)
#pragma unroll
        for (int j = 0; j < 4; ++j)
            acc[i][j] = (f32x4){0.f, 0.f, 0.f, 0.f};

    const int kbase = sp * 512;
    for (int kt = 0; kt < 16; ++kt) {
        const int kk = kbase + kt * 32;
        int4 a0 = *(const int4*)(A + (size_t)(trow + r0) * K1 + kk + kq0);
        int4 a1 = *(const int4*)(A + (size_t)(trow + 64 + r0) * K1 + kk + kq0);
        int4 b0 = *(const int4*)(B + (size_t)(tcol + r0) * K1 + kk + kq0);
        int4 b1 = *(const int4*)(B + (size_t)(tcol + 64 + r0) * K1 + kk + kq0);
        __syncthreads();
        *(int4*)&Al[r0][kq0] = a0;
        *(int4*)&Al[64 + r0][kq0] = a1;
        *(int4*)&Bl[r0][kq0] = b0;
        *(int4*)&Bl[64 + r0][kq0] = b1;
        __syncthreads();
        bf16x8 af[4], bfr[4];
#pragma unroll
        for (int i = 0; i < 4; ++i)
            af[i] = *(const bf16x8*)&Al[wr + i * 16 + l16][q * 8];
#pragma unroll
        for (int j = 0; j < 4; ++j)
            bfr[j] = *(const bf16x8*)&Bl[wc + j * 16 + l16][q * 8];
#pragma unroll
        for (int i = 0; i < 4; ++i)
#pragma unroll
            for (int j = 0; j < 4; ++j)
                acc[i][j] = __builtin_amdgcn_mfma_f32_16x16x32_bf16(af[i], bfr[j], acc[i][j], 0, 0, 0);
    }

    float* W = wpart + ((size_t)sp * 12 + ln) * (CC * CC);
#pragma unroll
    for (int i = 0; i < 4; ++i)
#pragma unroll
        for (int j = 0; j < 4; ++j) {
            const int ob = trow + wr + i * 16 + q * 4;   // D rows (4 consecutive o)
            const int b  = tcol + wc + j * 16 + l16;     // D col
            *(float4*)(W + (size_t)b * CC + ob) =
                (float4){acc[i][j][0], acc[i][j][1], acc[i][j][2], acc[i][j][3]};
        }
}

// ---------------------------------------------------------------------------
// Sum 8 split-K partials (layout [b][o]), fold BN row-scale(o), transpose via
// LDS, emit bf16 Ws[ln][o][b] coalesced. Grid (16 tiles, 12 ln).
__global__ __launch_bounds__(256) void reduce_kernel(const float* __restrict__ wpart,
                                                     const float* __restrict__ gamma,
                                                     const float* __restrict__ var,
                                                     ushort* __restrict__ Ws) {
    const int ln = blockIdx.y;
    const int l = ln >> 2;
    const int bt = blockIdx.x >> 2, ot = blockIdx.x & 3;
    __shared__ ushort T[64][72];
    __shared__ float scv[64];
    const int t = threadIdx.x;
    if (t < 64) {
        const int o = ot * 64 + t;
        scv[t] = gamma[l * CC + o] * rsqrtf(var[l * CC + o] + EPSV);
    }
    __syncthreads();
    const int bl = t >> 2, oc = (t & 3) * 16;
    const float* base = wpart + (size_t)ln * (CC * CC) + (size_t)(bt * 64 + bl) * CC + ot * 64 + oc;
    float s[16] = {};
#pragma unroll
    for (int sp = 0; sp < 8; ++sp) {
        const float* p = base + (size_t)sp * 12 * CC * CC;
#pragma unroll
        for (int c = 0; c < 4; ++c) {
            float4 v = *(const float4*)(p + c * 4);
            s[c * 4 + 0] += v.x; s[c * 4 + 1] += v.y;
            s[c * 4 + 2] += v.z; s[c * 4 + 3] += v.w;
        }
    }
#pragma unroll
    for (int e = 0; e < 16; ++e)
        T[oc + e][bl] = f2bf(s[e] * scv[oc + e]);
    __syncthreads();
    const int ol = t >> 2, b0 = (t & 3) * 16;
    ushort* dst = Ws + ((size_t)ln * CC + ot * 64 + ol) * CC + bt * 64 + b0;
#pragma unroll
    for (int c = 0; c < 4; ++c) {
        ushort4 o = {T[ol][b0 + c * 4 + 0], T[ol][b0 + c * 4 + 1],
                     T[ol][b0 + c * 4 + 2], T[ol][b0 + c * 4 + 3]};
        *(ushort4*)(dst + c * 4) = o;
    }
}

// ---------------------------------------------------------------------------
// Layer GEMM (bf16 MFMA, TN): yT[p][o] = sum_b xT[p][b] * Ws[o][b].
// Epilogue: bias+relu into LDS tile S[64p][64o], then coalesced stores:
//   out[n][o][p]: 4 thr/row -> 256 B runs;  xT[p][c]: 4 thr/row -> 128 B runs.
__global__ __launch_bounds__(256) void layer_mfma(const ushort* __restrict__ xT,
                                                  const ushort* __restrict__ Wsl,
                                                  const float* __restrict__ convb_l,
                                                  const float* __restrict__ gamma_l,
                                                  const float* __restrict__ beta_l,
                                                  const float* __restrict__ mean_l,
                                                  const float* __restrict__ var_l,
                                                  float* __restrict__ outl,
                                                  ushort* __restrict__ xTn) {
    const int n = blockIdx.y;
    const int pt = blockIdx.x & 15, ot = blockIdx.x >> 4;
    const ushort* Axt = xT + (size_t)n * HWP * CC + (size_t)pt * 64 * CC;
    const ushort* Bw  = Wsl + (size_t)n * CC * CC + (size_t)ot * 64 * CC;
    __shared__ ushort Al[64][40];
    __shared__ ushort Bl[64][40];
    __shared__ float S[64][68];           // [p_local][o_local], 2-way max on acc writes
    const int t = threadIdx.x;
    const int wv = t >> 6, L = t & 63;
    const int wr = (wv >> 1) * 32, wc = (wv & 1) * 32;
    const int l16 = L & 15, q = L >> 4;
    const int r0 = t >> 2, kq0 = (t & 3) * 8;
    f32x4 acc[2][2];
#pragma unroll
    for (int i = 0; i < 2; ++i)
#pragma unroll
        for (int j = 0; j < 2; ++j)
            acc[i][j] = (f32x4){0.f, 0.f, 0.f, 0.f};

    for (int kt = 0; kt < 8; ++kt) {
        const int kk = kt * 32;
        int4 av = *(const int4*)(Axt + (size_t)r0 * CC + kk + kq0);
        int4 bv = *(const int4*)(Bw + (size_t)r0 * CC + kk + kq0);
        __syncthreads();
        *(int4*)&Al[r0][kq0] = av;
        *(int4*)&Bl[r0][kq0] = bv;
        __syncthreads();
        bf16x8 af[2], bfr[2];
#pragma unroll
        for (int i = 0; i < 2; ++i)
            af[i] = *(const bf16x8*)&Al[wr + i * 16 + l16][q * 8];
#pragma unroll
        for (int j = 0; j < 2; ++j)
            bfr[j] = *(const bf16x8*)&Bl[wc + j * 16 + l16][q * 8];
#pragma unroll
        for (int i = 0; i < 2; ++i)
#pragma unroll
            for (int j = 0; j < 2; ++j)
                acc[i][j] = __builtin_amdgcn_mfma_f32_16x16x32_bf16(af[i], bfr[j], acc[i][j], 0, 0, 0);
    }

    // bias + relu -> LDS tile
#pragma unroll
    for (int j = 0; j < 2; ++j) {
        const int ol = wc + j * 16 + l16;
        const int og = ot * 64 + ol;
        const float sc = gamma_l[og] * rsqrtf(var_l[og] + EPSV);
        const float b2 = sc * (convb_l[og] - mean_l[og]) + beta_l[og];
#pragma unroll
        for (int i = 0; i < 2; ++i) {
            const int pl = wr + i * 16 + q * 4;
            S[pl + 0][ol] = fmaxf(acc[i][j][0] + b2, 0.f);
            S[pl + 1][ol] = fmaxf(acc[i][j][1] + b2, 0.f);
            S[pl + 2][ol] = fmaxf(acc[i][j][2] + b2, 0.f);
            S[pl + 3][ol] = fmaxf(acc[i][j][3] + b2, 0.f);
        }
    }
    __syncthreads();

    float* outn = outl + (size_t)n * CC * HWP;
    ushort* xtn = xTn + (size_t)n * HWP * CC;
    {   // out[n][o][p]: thread = (o_local, p-quarter)
        const int ol = t >> 2, p0 = (t & 3) * 16;
        float* op = outn + (size_t)(ot * 64 + ol) * HWP + pt * 64 + p0;
#pragma unroll
        for (int c = 0; c < 4; ++c) {
            float4 v = {S[p0 + c * 4 + 0][ol], S[p0 + c * 4 + 1][ol],
                        S[p0 + c * 4 + 2][ol], S[p0 + c * 4 + 3][ol]};
            *(float4*)(op + c * 4) = v;
        }
    }
    {   // xT[p][c]: thread = (p_local, c-quarter)
        const int pl = t >> 2, c0 = (t & 3) * 16;
        ushort* xp = xtn + (size_t)(pt * 64 + pl) * CC + ot * 64 + c0;
#pragma unroll
        for (int c = 0; c < 4; ++c) {
            ushort4 o = {f2bf(S[pl][c0 + c * 4 + 0]), f2bf(S[pl][c0 + c * 4 + 1]),
                         f2bf(S[pl][c0 + c * 4 + 2]), f2bf(S[pl][c0 + c * 4 + 3])};
            *(ushort4*)(xp + c * 4) = o;
        }
    }
}

// ---------------------------------------------------------------------------
extern "C" void kernel_launch(void* const* d_in, const int* in_sizes, int n_in,
                              void* d_out, int out_size, void* d_ws, size_t ws_size,
                              hipStream_t stream) {
    const float* feats  = (const float*)d_in[0];
    const float* adj    = (const float*)d_in[1];
    const float* conv_w = (const float*)d_in[2];
    const float* conv_b = (const float*)d_in[3];
    const float* gamma  = (const float*)d_in[4];
    const float* beta   = (const float*)d_in[5];
    const float* mean   = (const float*)d_in[6];
    const float* var    = (const float*)d_in[7];
    float* out = (float*)d_out;

    // ws layout (bytes):
    //   [0, 64K) flags | [+6291456) convwb | [+8388608) msst | [+1572864) Ws
    //   [+2097152) fT0 | [+25165824) wpart fp32 [8][12][b][o] (aliased by xT1..3)
    char* ws = (char*)d_ws;
    uint8_t* flags  = (uint8_t*)ws;
    ushort*  convwb = (ushort*)(ws + 65536);
    ushort*  msst   = (ushort*)(ws + 65536 + 6291456);
    ushort*  Wsb    = (ushort*)(ws + 65536 + 6291456 + 8388608);
    ushort*  fT0    = (ushort*)(ws + 65536 + 6291456 + 8388608 + 1572864);
    float*   wpart  = (float*)(ws + 65536 + 6291456 + 8388608 + 1572864 + 2097152);
    ushort*  xT1    = (ushort*)wpart;                    // safe: wpart consumed by reduce
    ushort*  xT2    = xT1 + (size_t)NB * HWP * CC;
    ushort*  xT3    = xT2 + (size_t)NB * HWP * CC;

    prep1_kernel<<<1088, 256, 0, stream>>>(adj, feats, conv_w, flags, fT0, convwb);
    msst_kernel<<<dim3(16, NB), 256, 0, stream>>>(adj, flags, msst);
    weff_mfma<<<dim3(4, 12, 8), 256, 0, stream>>>(convwb, msst, wpart);
    reduce_kernel<<<dim3(16, 12), 256, 0, stream>>>(wpart, gamma, var, Wsb);

    const ushort* xin[3] = {fT0, xT1, xT2};
    ushort* xout[3] = {xT1, xT2, xT3};
    for (int l = 0; l < 3; ++l) {
        layer_mfma<<<dim3(64, NB), 256, 0, stream>>>(
            xin[l], Wsb + (size_t)l * NB * CC * CC,
            conv_b + l * CC, gamma + l * CC, beta + l * CC, mean + l * CC, var + l * CC,
            out + (size_t)l * NB * CC * HWP, xout[l]);
    }
}